// Round 8
// baseline (651.398 us; speedup 1.0000x reference)
//
#include <hip/hip_runtime.h>

#define SEQ   2048
#define BATCH 4096
#define HID   6
#define BLK   256   // 4 waves/block; 256 blocks -> 1 block/CU, 1 wave/SIMD

typedef float v2f __attribute__((ext_vector_type(2)));
typedef unsigned u2 __attribute__((ext_vector_type(2)));

// ---- fast HW math ----
__device__ __forceinline__ float fexp2(float a) {
#if __has_builtin(__builtin_amdgcn_exp2f)
  return __builtin_amdgcn_exp2f(a);
#else
  float r; asm("v_exp_f32 %0, %1" : "=v"(r) : "v"(a)); return r;
#endif
}
__device__ __forceinline__ float frcp(float a) {
#if __has_builtin(__builtin_amdgcn_rcpf)
  return __builtin_amdgcn_rcpf(a);
#else
  float r; asm("v_rcp_f32 %0, %1" : "=v"(r) : "v"(a)); return r;
#endif
}

// ---- DPP cross-lane (VALU pipe, ~4cy latency; no LDS round-trip) ----
template <int CTRL>
__device__ __forceinline__ float dppf(float v) {
  int r = __builtin_amdgcn_update_dpp(0, __builtin_bit_cast(int, v), CTRL, 0xF, 0xF, true);
  return __builtin_bit_cast(float, r);
}
// DPP ctrl: 0xB1 quad_perm[1,0,3,2]=xor1; 0x4E quad_perm[2,3,0,1]=xor2;
// 0x141 row_half_mirror: lane i -> 7-i within 8-half == xor7 on the 8-group.

// lane l <-> l^32 exchange via v_permlane32_swap_b32 (polarity validated by R7 PASS)
__device__ __forceinline__ float xhalf(float v, bool hi) {
#if __has_builtin(__builtin_amdgcn_permlane32_swap)
  u2 r = __builtin_amdgcn_permlane32_swap(__builtin_bit_cast(unsigned, v),
                                          __builtin_bit_cast(unsigned, v), false, false);
  return __builtin_bit_cast(float, hi ? r.x : r.y);
#else
  unsigned d = __builtin_bit_cast(unsigned, v), s = d;
  asm volatile("v_permlane32_swap_b32 %0, %1" : "+v"(d), "+v"(s));
  return __builtin_bit_cast(float, hi ? d : s);
#endif
}

__global__ __launch_bounds__(BLK, 1) void lstm2_kernel(
    const float* __restrict__ x,
    const float* __restrict__ Wih0, const float* __restrict__ Whh0,
    const float* __restrict__ bih0, const float* __restrict__ bhh0,
    const float* __restrict__ Wih1, const float* __restrict__ Whh1,
    const float* __restrict__ bih1, const float* __restrict__ bhh1,
    const float* __restrict__ W2,   const float* __restrict__ b2,
    float* __restrict__ out)
{
  __shared__ float obuf[64][16];   // output rows staged; bulk-flushed every 64 steps

  const int tid = threadIdx.x;
  const int wib = tid >> 6;            // wave in block 0..3
  const int l6  = tid & 63;
  const bool hi = l6 >= 32;            // false: layer-0 lanes, true: layer-1 lanes
  const int j   = l6 & 31;
  const int el  = j >> 3;              // element within wave 0..3
  const int u   = j & 7;               // unit 0..7 (6,7 pads)
  const int uu  = (u < HID) ? u : (HID - 1);   // clamp: pad lanes compute real (finite) rows
  const int b   = blockIdx.x * 16 + wib * 4 + el;   // batch element

  // Per-row constants, rows q = 0..3 (i,f,g,o); gate scale K folded into
  // weights+bias. Weight pairs in XOR-RELATIVE unit order: slot k holds
  // {W[row][u^2k], W[row][u^2k+1]}, zero for pad columns (>=HID).
  v2f WA[4][4], WB[4][4], w2r[4];
  float BS[4];
#pragma unroll
  for (int q = 0; q < 4; ++q) {
    const int rq = q * HID + uu;
    const float Kq = (q == 2) ? -2.8853900817779268f : -1.4426950408889634f;
#pragma unroll
    for (int k = 0; k < 4; ++k) {
      const int k0 = u ^ (2 * k), k1 = u ^ (2 * k + 1);
      const bool ok0 = (k0 < HID), ok1 = (k1 < HID);
      if (!hi) {
        WA[q][k] = v2f{0.f, 0.f};    // lo: input term is x (handled via slot 0 below)
        WB[q][k] = v2f{ok0 ? Kq * Whh0[rq * HID + k0] : 0.f,
                       ok1 ? Kq * Whh0[rq * HID + k1] : 0.f};
      } else {
        WA[q][k] = v2f{ok0 ? Kq * Wih1[rq * HID + k0] : 0.f,
                       ok1 ? Kq * Wih1[rq * HID + k1] : 0.f};
        WB[q][k] = v2f{ok0 ? Kq * Whh1[rq * HID + k0] : 0.f,
                       ok1 ? Kq * Whh1[rq * HID + k1] : 0.f};
      }
    }
    if (!hi) WA[q][0] = v2f{Kq * Wih0[rq * 2 + 0], Kq * Wih0[rq * 2 + 1]};  // x pair
    BS[q] = Kq * ((!hi ? bih0[rq] : bih1[rq]) + (!hi ? bhh0[rq] : bhh1[rq]));
  }
#pragma unroll
  for (int k = 0; k < 4; ++k) {
    const int k0 = u ^ (2 * k), k1 = u ^ (2 * k + 1);
    w2r[k] = v2f{(k0 < HID) ? W2[k0] : 0.f, (k1 < HID) ? W2[k1] : 0.f};
  }
  const float bout = b2[0];
  const float KT = 2.8853900817779268f;   // tanh(c) = 1 - 2*rcp(1+exp2(KT*c))

  float h = 0.f, c = 0.f;   // own-layer state: lo = (h0,c0), hi = (h1,c1)

  // xor-relative all-gather over the 8-group, pure DPP (7 ops, depth 2):
  // g[k] = {h[u^2k], h[u^2k+1]}
  auto gath = [&](float hv, v2f (&g)[4]) {
    float t1 = dppf<0xB1>(hv);       // xor1
    float t2 = dppf<0x4E>(hv);       // xor2
    float t3 = dppf<0x4E>(t1);       // xor3
    float m  = dppf<0x141>(hv);      // row_half_mirror = xor7
    float m1 = dppf<0xB1>(m);        // xor6
    float m2 = dppf<0x4E>(m);        // xor5
    float m3 = dppf<0x4E>(m1);       // xor4
    g[0] = v2f{hv, t1};
    g[1] = v2f{t2, t3};
    g[2] = v2f{m3, m2};
    g[3] = v2f{m1, m};
  };

  // one fused step: lo computes L0 cell (x, h0-rec), hi computes L1 cell
  // (h0 via permlane32 swap, h1-rec). ov = out-dot of hi's own-layer gather.
  auto step = [&](v2f xc, float& ov) {
    v2f g2[4]; gath(h, g2);                 // own-layer recurrence input
    float hs = xhalf(h, hi);                // hi lanes: partner h0[t-1]
    v2f g1[4]; gath(hs, g1);                // L1's input gather (lo: finite garbage)
    v2f v10 = hi ? g1[0] : xc;              // lo: x pair

    float a[4];
#pragma unroll
    for (int q = 0; q < 4; ++q) {
      v2f accA = __builtin_elementwise_fma(WA[q][0], v10, v2f{BS[q], 0.f});
      accA = __builtin_elementwise_fma(WA[q][1], g1[1], accA);
      accA = __builtin_elementwise_fma(WA[q][2], g1[2], accA);
      accA = __builtin_elementwise_fma(WA[q][3], g1[3], accA);
      v2f accB = WB[q][0] * g2[0];
      accB = __builtin_elementwise_fma(WB[q][1], g2[1], accB);
      accB = __builtin_elementwise_fma(WB[q][2], g2[2], accB);
      accB = __builtin_elementwise_fma(WB[q][3], g2[3], accB);
      v2f acc = accA + accB;
      a[q] = acc.x + acc.y;
    }
    // output row dot from hi's g2 = h1g[t-2]
    v2f ao = __builtin_elementwise_fma(w2r[0], g2[0],
             __builtin_elementwise_fma(w2r[1], g2[1],
             __builtin_elementwise_fma(w2r[2], g2[2],
             __builtin_elementwise_fma(w2r[3], g2[3], v2f{bout, 0.f}))));
    ov = ao.x + ao.y;

    // gates (a pre-scaled): sigma = rcp(1+exp2(a)); g-gate = 2*sigma-1
    float i_ = frcp(1.f + fexp2(a[0]));
    float f_ = frcp(1.f + fexp2(a[1]));
    float g_ = fmaf(2.f, frcp(1.f + fexp2(a[2])), -1.f);
    float o_ = frcp(1.f + fexp2(a[3]));
    c = fmaf(f_, c, i_ * g_);
    float th = fmaf(-2.f, frcp(1.f + fexp2(c * KT)), 1.f);
    h = o_ * th;
  };

  // bulk flush: 64 rows x 16 elements as float4 per thread (full 64B lines)
  auto flush = [&](int rbase) {
    const int r = tid >> 2, jj = (tid & 3) * 4;
    float4 vv = *(const float4*)&obuf[r][jj];
    *(float4*)&out[(size_t)(rbase + r) * BATCH + blockIdx.x * 16 + jj] = vv;
  };

  const v2f* x2 = (const v2f*)x;
  // x prefetch queue, depth 4; invariant at loop-entry t: (xc..xn3) = x[t..t+3]
  v2f xc  = x2[(size_t)0 * BATCH + b];
  v2f xn1 = x2[(size_t)1 * BATCH + b];
  v2f xn2 = x2[(size_t)2 * BATCH + b];
  v2f xn3 = x2[(size_t)3 * BATCH + b];

  // t = 0 peel: lo computes h0[0]; hi's result is pre-sequence garbage -> reset
  {
    float ov;
    step(xc, ov);
    if (hi) { h = 0.f; c = 0.f; }
    v2f xf = x2[(size_t)4 * BATCH + b];
    xc = xn1; xn1 = xn2; xn2 = xn3; xn3 = xf;
  }

  // iteration t: lo -> h0[t] (x[t], h0[t-1]); hi -> h1[t-1] (h0[t-1], h1[t-2]);
  // out row t-2 from hi's recurrence gather.
#pragma unroll 1
  for (int t = 1; t < SEQ; ++t) {
    int tf = t + 4; tf = (tf < SEQ) ? tf : (SEQ - 1);
    v2f xf = x2[(size_t)tf * BATCH + b];

    float ov;
    step(xc, ov);

    if (t >= 2) {
      const int r = t - 2;
      if (hi && u == 0) obuf[r & 63][wib * 4 + el] = ov;
      if ((r & 63) == 63) {          // uniform branch
        __syncthreads();
        flush(r - 63);
        __syncthreads();
      }
    }
    xc = xn1; xn1 = xn2; xn2 = xn3; xn3 = xf;
  }

  // epilogue: one more fused step -> h1[S-1] + out row S-2; final gather -> row S-1
  {
    float ov;
    step(xc, ov);
    if (hi && u == 0) obuf[62][wib * 4 + el] = ov;
    v2f g2[4]; gath(h, g2);
    v2f ao = __builtin_elementwise_fma(w2r[0], g2[0],
             __builtin_elementwise_fma(w2r[1], g2[1],
             __builtin_elementwise_fma(w2r[2], g2[2],
             __builtin_elementwise_fma(w2r[3], g2[3], v2f{bout, 0.f}))));
    if (hi && u == 0) obuf[63][wib * 4 + el] = ao.x + ao.y;
    __syncthreads();
    flush(SEQ - 64);
  }
}

extern "C" void kernel_launch(void* const* d_in, const int* in_sizes, int n_in,
                              void* d_out, int out_size, void* d_ws, size_t ws_size,
                              hipStream_t stream) {
  const float* x    = (const float*)d_in[0];
  const float* Wih0 = (const float*)d_in[1];
  const float* Whh0 = (const float*)d_in[2];
  const float* bih0 = (const float*)d_in[3];
  const float* bhh0 = (const float*)d_in[4];
  const float* Wih1 = (const float*)d_in[5];
  const float* Whh1 = (const float*)d_in[6];
  const float* bih1 = (const float*)d_in[7];
  const float* bhh1 = (const float*)d_in[8];
  const float* W2   = (const float*)d_in[9];
  const float* b2   = (const float*)d_in[10];
  float* out = (float*)d_out;

  dim3 grid(BATCH / 16);   // 256 blocks x 4 waves = 1024 waves = 1 wave/SIMD
  dim3 block(BLK);
  hipLaunchKernelGGL(lstm2_kernel, grid, block, 0, stream,
                     x, Wih0, Whh0, bih0, bhh0, Wih1, Whh1, bih1, bhh1, W2, b2, out);
}